// Round 21
// baseline (728.499 us; speedup 1.0000x reference)
//
#include <hip/hip_runtime.h>

// Refine: out = relu((1-a)*(W f) + a*chat[idx] + bias)
// a = exp(-(csq - 2*<f,cent[idx]> + fsq)/256), chat = W*cent
// idx = argmax_n <f, cnorm_n>
//
// ws layout (1 GiB available; ~88 MB used):
//  cnT    [256][80] f32        @ 0
//  wt     [256][256] f32       @ 81920
//  wks    [8][256][32] bf16    @ 344064
//  centf  [16][80][256] bf16   @ 475136
//  idxb   [16*16384] u8        @ 1130496
//  fsq    [16*16384] f32       @ 1392640
//  cnt    [16*80] i32          @ 2441216  (zeroed by k0_cnorm)
//  csq    [16*80] f32          @ 2446336
//  chat   [16][80][256] f32    @ 2451456
//  part   [16][64][80][256] f32 @ 3762176  (per-block sumx partials, NON-atomic)

typedef __bf16 bf16x8 __attribute__((ext_vector_type(8)));
typedef float  f32x4  __attribute__((ext_vector_type(4)));
typedef unsigned char u8;

__device__ __forceinline__ unsigned short f2b(float f) {
  unsigned u = __float_as_uint(f);
  return (unsigned short)((u + 0x7fffu + ((u >> 16) & 1u)) >> 16);
}
__device__ __forceinline__ float b2f(unsigned short s) {
  return __uint_as_float((unsigned)s << 16);
}

// ---------------- K0a: normalized centroids [c][n] + zero cntg ----------------
__global__ __launch_bounds__(256) void k0_cnorm(const float* __restrict__ cent,
                                                float* __restrict__ cnT,
                                                int* __restrict__ cntg) {
  int n = blockIdx.x, t = threadIdx.x;
  if (t < 16) cntg[n * 16 + t] = 0;
  float v = cent[n * 256 + t];
  float s = v * v;
  #pragma unroll
  for (int o = 32; o > 0; o >>= 1) s += __shfl_down(s, o, 64);
  __shared__ float red[4];
  if ((t & 63) == 0) red[t >> 6] = s;
  __syncthreads();
  float tot = red[0] + red[1] + red[2] + red[3];
  float dn = fmaxf(sqrtf(tot), 1e-12f);
  cnT[t * 80 + n] = v / dn;
}

// ---------------- K0b: W prep: bf16 k-sliced [k][o][32] + W^T f32 -------------
__global__ __launch_bounds__(256) void k0_wprep(const float* __restrict__ fcw,
                                                unsigned short* __restrict__ wks,
                                                float* __restrict__ wt) {
  int o = blockIdx.x, c = threadIdx.x;
  float w = fcw[o * 256 + c];
  wt[c * 256 + o] = w;
  wks[((c >> 5) * 256 + o) * 32 + (c & 31)] = f2b(w);
}

// ---- K1F_V8: 4 class-quarter argmax + 4 channel-quarter sumx -----------------
// Target: <=64 unified regs (g[20]=20V peak argmax; acc[5]=20 AGPR sumx)
// -> 8 waves/SIMD. Identical math/order to v4 (bit-identical outputs).
__global__ __launch_bounds__(256, 8) void k1f_v8(const float* __restrict__ feat,
                                                 const float* __restrict__ cnT,
                                                 u8* __restrict__ idxb,
                                                 float* __restrict__ fsqg,
                                                 int* __restrict__ cntg,
                                                 float* __restrict__ part,
                                                 int cbase) {
  __shared__ alignas(8) u8 idxl[256];
  __shared__ int lh[80];
  const int b = blockIdx.x >> 5, chunk = cbase + (blockIdx.x & 31);
  const int px0 = chunk << 8;
  const int t = threadIdx.x, wv = t >> 6, ln = t & 63, lo = ln & 15, hi = ln >> 4;
  if (t < 80) lh[t] = 0;
  __syncthreads();

  const int pi = px0 | t;
  const float* fb = feat + (size_t)b * 256 * 16384 + pi;
  float best, fsq; int bi;
  { // quarter 0 (classes 0..19) + fsq
    float g[20];
    #pragma unroll
    for (int n = 0; n < 20; ++n) g[n] = 0.f;
    fsq = 0.f;
    #pragma unroll 4
    for (int c = 0; c < 256; ++c) {
      float v = fb[(size_t)c * 16384];
      fsq = fmaf(v, v, fsq);
      const float* cr = cnT + c * 80;
      #pragma unroll
      for (int n = 0; n < 20; ++n) g[n] = fmaf(v, cr[n], g[n]);
    }
    best = g[0]; bi = 0;
    #pragma unroll
    for (int n = 1; n < 20; ++n) if (g[n] > best) { best = g[n]; bi = n; }
  }
  #pragma unroll 1
  for (int q = 1; q < 4; ++q) {  // quarters 1..3 (L2/L3-hot re-reads)
    float g[20];
    #pragma unroll
    for (int n = 0; n < 20; ++n) g[n] = 0.f;
    #pragma unroll 4
    for (int c = 0; c < 256; ++c) {
      float v = fb[(size_t)c * 16384];
      const float* cr = cnT + c * 80 + q * 20;
      #pragma unroll
      for (int n = 0; n < 20; ++n) g[n] = fmaf(v, cr[n], g[n]);
    }
    float bq = g[0]; int iq = q * 20;
    #pragma unroll
    for (int n = 1; n < 20; ++n) if (g[n] > bq) { bq = g[n]; iq = q * 20 + n; }
    if (bq > best) { best = bq; bi = iq; }        // ascending q -> first-max kept
  }
  idxb[b * 16384 + pi] = (u8)bi;
  fsqg[b * 16384 + pi] = fsq;
  idxl[t] = (u8)bi;
  atomicAdd(&lh[bi], 1);
  __syncthreads();
  if (t < 80) atomicAdd(&cntg[b * 80 + t], lh[t]);

  // sumx: one-hot MFMA, 4 channel-quarter passes (acc[5] = 20 AGPR)
  const int chb = wv * 64;
  float* pb = part + ((size_t)(b * 64 + chunk) * 80) * 256;
  #pragma unroll 1
  for (int qt = 0; qt < 4; ++qt) {
    f32x4 acc[5];
    f32x4 zz = {0.f, 0.f, 0.f, 0.f};
    #pragma unroll
    for (int mt = 0; mt < 5; ++mt) acc[mt] = zz;
    #pragma unroll 2
    for (int ks = 0; ks < 8; ++ks) {
      uint2 iv = *(const uint2*)&idxl[ks * 32 + hi * 8];
      int id[8];
      #pragma unroll
      for (int j = 0; j < 4; ++j) { id[j] = (iv.x >> (8 * j)) & 255; id[4 + j] = (iv.y >> (8 * j)) & 255; }
      const float* bp = feat + ((size_t)b * 256 + chb + qt * 16 + lo) * 16384 + px0 + ks * 32 + hi * 8;
      float4 v0 = *(const float4*)bp;
      float4 v1 = *(const float4*)(bp + 4);
      union { unsigned short u[8]; bf16x8 v; } bb;
      bb.u[0] = f2b(v0.x); bb.u[1] = f2b(v0.y); bb.u[2] = f2b(v0.z); bb.u[3] = f2b(v0.w);
      bb.u[4] = f2b(v1.x); bb.u[5] = f2b(v1.y); bb.u[6] = f2b(v1.z); bb.u[7] = f2b(v1.w);
      #pragma unroll
      for (int mt = 0; mt < 5; ++mt) {
        int row = mt * 16 + lo;
        union { unsigned short u[8]; bf16x8 v; } ma;
        #pragma unroll
        for (int j = 0; j < 8; ++j) ma.u[j] = (id[j] == row) ? (unsigned short)0x3F80 : (unsigned short)0;
        acc[mt] = __builtin_amdgcn_mfma_f32_16x16x32_bf16(ma.v, bb.v, acc[mt], 0, 0, 0);
      }
    }
    #pragma unroll
    for (int mt = 0; mt < 5; ++mt)
      #pragma unroll
      for (int r = 0; r < 4; ++r)
        pb[(mt * 16 + hi * 4 + r) * 256 + chb + qt * 16 + lo] = acc[mt][r];
  }
}

// ---- K1F_V4: R20-exact (proven 214 us over 64 chunks) ------------------------
__global__ __launch_bounds__(256, 4) void k1f_v4(const float* __restrict__ feat,
                                                 const float* __restrict__ cnT,
                                                 u8* __restrict__ idxb,
                                                 float* __restrict__ fsqg,
                                                 int* __restrict__ cntg,
                                                 float* __restrict__ part,
                                                 int cbase) {
  __shared__ alignas(8) u8 idxl[256];
  __shared__ int lh[80];
  const int b = blockIdx.x >> 5, chunk = cbase + (blockIdx.x & 31);
  const int px0 = chunk << 8;
  const int t = threadIdx.x, wv = t >> 6, ln = t & 63, lo = ln & 15, hi = ln >> 4;
  if (t < 80) lh[t] = 0;
  __syncthreads();

  const int pi = px0 | t;
  const float* fb = feat + (size_t)b * 256 * 16384 + pi;
  float best, fsq; int bi;
  {
    float g[40];
    #pragma unroll
    for (int n = 0; n < 40; ++n) g[n] = 0.f;
    fsq = 0.f;
    #pragma unroll 4
    for (int c = 0; c < 256; ++c) {
      float v = fb[(size_t)c * 16384];
      fsq = fmaf(v, v, fsq);
      const float* cr = cnT + c * 80;
      #pragma unroll
      for (int n = 0; n < 40; ++n) g[n] = fmaf(v, cr[n], g[n]);
    }
    best = g[0]; bi = 0;
    #pragma unroll
    for (int n = 1; n < 40; ++n) if (g[n] > best) { best = g[n]; bi = n; }
  }
  {
    float g[40];
    #pragma unroll
    for (int n = 0; n < 40; ++n) g[n] = 0.f;
    #pragma unroll 4
    for (int c = 0; c < 256; ++c) {
      float v = fb[(size_t)c * 16384];
      const float* cr = cnT + c * 80 + 40;
      #pragma unroll
      for (int n = 0; n < 40; ++n) g[n] = fmaf(v, cr[n], g[n]);
    }
    float b2 = g[0]; int i2 = 40;
    #pragma unroll
    for (int n = 1; n < 40; ++n) if (g[n] > b2) { b2 = g[n]; i2 = 40 + n; }
    if (b2 > best) { best = b2; bi = i2; }
  }
  idxb[b * 16384 + pi] = (u8)bi;
  fsqg[b * 16384 + pi] = fsq;
  idxl[t] = (u8)bi;
  atomicAdd(&lh[bi], 1);
  __syncthreads();
  if (t < 80) atomicAdd(&cntg[b * 80 + t], lh[t]);

  const int chb = wv * 64;
  float* pb = part + ((size_t)(b * 64 + chunk) * 80) * 256;
  #pragma unroll 1
  for (int half = 0; half < 2; ++half) {
    f32x4 acc[5][2];
    f32x4 zz = {0.f, 0.f, 0.f, 0.f};
    #pragma unroll
    for (int mt = 0; mt < 5; ++mt) { acc[mt][0] = zz; acc[mt][1] = zz; }
    #pragma unroll 2
    for (int ks = 0; ks < 8; ++ks) {
      uint2 iv = *(const uint2*)&idxl[ks * 32 + hi * 8];
      int id[8];
      #pragma unroll
      for (int j = 0; j < 4; ++j) { id[j] = (iv.x >> (8 * j)) & 255; id[4 + j] = (iv.y >> (8 * j)) & 255; }
      bf16x8 bfr[2];
      #pragma unroll
      for (int n2 = 0; n2 < 2; ++n2) {
        int nt = half * 2 + n2;
        const float* bp = feat + ((size_t)b * 256 + chb + nt * 16 + lo) * 16384 + px0 + ks * 32 + hi * 8;
        float4 v0 = *(const float4*)bp;
        float4 v1 = *(const float4*)(bp + 4);
        union { unsigned short u[8]; bf16x8 v; } bb;
        bb.u[0] = f2b(v0.x); bb.u[1] = f2b(v0.y); bb.u[2] = f2b(v0.z); bb.u[3] = f2b(v0.w);
        bb.u[4] = f2b(v1.x); bb.u[5] = f2b(v1.y); bb.u[6] = f2b(v1.z); bb.u[7] = f2b(v1.w);
        bfr[n2] = bb.v;
      }
      #pragma unroll
      for (int mt = 0; mt < 5; ++mt) {
        int row = mt * 16 + lo;
        union { unsigned short u[8]; bf16x8 v; } ma;
        #pragma unroll
        for (int j = 0; j < 8; ++j) ma.u[j] = (id[j] == row) ? (unsigned short)0x3F80 : (unsigned short)0;
        #pragma unroll
        for (int n2 = 0; n2 < 2; ++n2)
          acc[mt][n2] = __builtin_amdgcn_mfma_f32_16x16x32_bf16(ma.v, bfr[n2], acc[mt][n2], 0, 0, 0);
      }
    }
    #pragma unroll
    for (int mt = 0; mt < 5; ++mt)
      #pragma unroll
      for (int n2 = 0; n2 < 2; ++n2)
        #pragma unroll
        for (int r = 0; r < 4; ++r)
          pb[(mt * 16 + hi * 4 + r) * 256 + chb + (half * 2 + n2) * 16 + lo] = acc[mt][n2][r];
  }
}

// -------- K2: cent = Σ64 partials / max(cnt,1); csq; centf; chat = W*cent -----
__global__ __launch_bounds__(256) void k2_cent(const float* __restrict__ part,
                                               const int* __restrict__ cntg,
                                               const float* __restrict__ wt,
                                               unsigned short* __restrict__ centf,
                                               float* __restrict__ csqg,
                                               float* __restrict__ chatg) {
  int bn = blockIdx.x; int b = bn / 80, n = bn - b * 80; int t = threadIdx.x;
  float dn = fmaxf((float)cntg[bn], 1.0f);
  float s = 0.f;
  const float* pp = part + ((size_t)(b * 64) * 80 + n) * 256 + t;
  #pragma unroll 8
  for (int ck = 0; ck < 64; ++ck) s += pp[(size_t)ck * 80 * 256];
  float cv = s / dn;
  __shared__ float cl[256];
  __shared__ float red[4];
  cl[t] = cv;
  centf[(size_t)bn * 256 + t] = f2b(cv);
  float q = cv * cv;
  #pragma unroll
  for (int o = 32; o > 0; o >>= 1) q += __shfl_down(q, o, 64);
  if ((t & 63) == 0) red[t >> 6] = q;
  __syncthreads();
  if (t == 0) csqg[bn] = red[0] + red[1] + red[2] + red[3];
  float acc = 0.f;
  #pragma unroll 4
  for (int c = 0; c < 256; ++c) acc = fmaf(wt[c * 256 + t], cl[c], acc);
  chatg[(size_t)bn * 256 + t] = acc;
}

// ---------------- K3b: pipelined W-in-registers MFMA GEMM + alpha + epilogue --
__global__ __launch_bounds__(512) void k3b_gemm(const float* __restrict__ feat,
    const u8* __restrict__ idxb, const float* __restrict__ fsqg,
    const float* __restrict__ csqg, const unsigned short* __restrict__ centf,
    const float* __restrict__ chatg, const unsigned short* __restrict__ wks,
    const float* __restrict__ fcb, float* __restrict__ out) {
  __shared__ alignas(16) unsigned short featT[2][64 * 264];  // double-buffered
  __shared__ float alphal[64];
  __shared__ int cidl[64];
  const int t = threadIdx.x;
  const int w = t >> 6, ln = t & 63, lo = ln & 15, hi = ln >> 4;
  const int pl = ln, cph = w;

  bf16x8 wf[2][8];
  #pragma unroll
  for (int ml = 0; ml < 2; ++ml)
    #pragma unroll
    for (int ks = 0; ks < 8; ++ks)
      wf[ml][ks] = *(const bf16x8*)&wks[((size_t)ks * 256 + (w * 2 + ml) * 16 + lo) * 32 + hi * 8];
  f32x4 bias2[2];
  #pragma unroll
  for (int ml = 0; ml < 2; ++ml)
    bias2[ml] = *(const f32x4*)&fcb[w * 32 + ml * 16 + hi * 4];

  const int tile0 = blockIdx.x * 8;
  {
    int b = tile0 >> 8, p0 = (tile0 & 255) << 6;
    const float* fb = feat + ((size_t)b * 256 + cph * 32) * 16384 + p0 + pl;
    #pragma unroll
    for (int jj = 0; jj < 4; ++jj) {
      union { unsigned short u[8]; uint4 q; } pk;
      #pragma unroll
      for (int e = 0; e < 8; ++e) pk.u[e] = f2b(fb[(size_t)(jj * 8 + e) * 16384]);
      *(uint4*)&featT[0][pl * 264 + cph * 32 + jj * 8] = pk.q;
    }
  }

  float nxv[32];
  for (int rep = 0; rep < 8; ++rep) {
    const int cur = rep & 1;
    const int tile = tile0 + rep;
    const int b = tile >> 8, p0 = (tile & 255) << 6;

    __syncthreads();

    if (rep < 7) {
      int t2 = tile + 1;
      int b2 = t2 >> 8, p02 = (t2 & 255) << 6;
      const float* fb2 = feat + ((size_t)b2 * 256 + cph * 32) * 16384 + p02 + pl;
      #pragma unroll
      for (int e = 0; e < 32; ++e) nxv[e] = fb2[(size_t)e * 16384];
    }

    {
      int p = t >> 3, sub = t & 7;
      int cid = idxb[b * 16384 + p0 + p];
      const unsigned short* cw = centf + ((size_t)b * 80 + cid) * 256 + sub * 32;
      const unsigned short* fr = &featT[cur][p * 264 + sub * 32];
      float sel = 0.f;
      #pragma unroll
      for (int j = 0; j < 4; ++j) {
        uint4 cc = *(const uint4*)&cw[j * 8];
        uint4 ff = *(const uint4*)&fr[j * 8];
        sel = fmaf(b2f((unsigned short)(ff.x & 0xffff)), b2f((unsigned short)(cc.x & 0xffff)), sel);
        sel = fmaf(b2f((unsigned short)(ff.x >> 16)),    b2f((unsigned short)(cc.x >> 16)),    sel);
        sel = fmaf(b2f((unsigned short)(ff.y & 0xffff)), b2f((unsigned short)(cc.y & 0xffff)), sel);
        sel = fmaf(b2f((unsigned short)(ff.y >> 16)),    b2f((unsigned short)(cc.y >> 16)),    sel);
        sel = fmaf(b2f((unsigned short)(ff.z & 0xffff)), b2f((unsigned short)(cc.z & 0xffff)), sel);
        sel = fmaf(b2f((unsigned short)(ff.z >> 16)),    b2f((unsigned short)(cc.z >> 16)),    sel);
        sel = fmaf(b2f((unsigned short)(ff.w & 0xffff)), b2f((unsigned short)(cc.w & 0xffff)), sel);
        sel = fmaf(b2f((unsigned short)(ff.w >> 16)),    b2f((unsigned short)(cc.w >> 16)),    sel);
      }
      sel += __shfl_xor(sel, 1, 64);
      sel += __shfl_xor(sel, 2, 64);
      sel += __shfl_xor(sel, 4, 64);
      if (sub == 0) {
        float fsq = fsqg[b * 16384 + p0 + p];
        float msq = (csqg[b * 80 + cid] - 2.f * sel + fsq) * (1.f / 256.f);
        alphal[p] = expf(-msq);
        cidl[p] = cid;
      }
    }

    f32x4 acc[2][4];
    f32x4 zz = {0.f, 0.f, 0.f, 0.f};
    #pragma unroll
    for (int ml = 0; ml < 2; ++ml)
      #pragma unroll
      for (int pt = 0; pt < 4; ++pt) acc[ml][pt] = zz;

    #pragma unroll
    for (int ks = 0; ks < 8; ++ks) {
      bf16x8 bfr[4];
      #pragma unroll
      for (int pt = 0; pt < 4; ++pt)
        bfr[pt] = *(const bf16x8*)&featT[cur][(pt * 16 + lo) * 264 + ks * 32 + hi * 8];
      #pragma unroll
      for (int ml = 0; ml < 2; ++ml)
        #pragma unroll
        for (int pt = 0; pt < 4; ++pt)
          acc[ml][pt] = __builtin_amdgcn_mfma_f32_16x16x32_bf16(wf[ml][ks], bfr[pt], acc[ml][pt], 0, 0, 0);
    }
    __syncthreads();

    #pragma unroll
    for (int pt = 0; pt < 4; ++pt) {
      int plx = pt * 16 + lo;
      int p = p0 + plx;
      float a = alphal[plx];
      float om = 1.f - a;
      const float* crow = chatg + ((size_t)b * 80 + cidl[plx]) * 256;
      #pragma unroll
      for (int ml = 0; ml < 2; ++ml) {
        int o0 = w * 32 + ml * 16 + hi * 4;
        float4 c4 = *(const float4*)&crow[o0];
        size_t ob = ((size_t)b * 256 + o0) * 16384 + p;
        out[ob            ] = fmaxf(fmaf(a, c4.x, om * acc[ml][pt][0]) + bias2[ml][0], 0.f);
        out[ob + 16384    ] = fmaxf(fmaf(a, c4.y, om * acc[ml][pt][1]) + bias2[ml][1], 0.f);
        out[ob + 2 * 16384] = fmaxf(fmaf(a, c4.z, om * acc[ml][pt][2]) + bias2[ml][2], 0.f);
        out[ob + 3 * 16384] = fmaxf(fmaf(a, c4.w, om * acc[ml][pt][3]) + bias2[ml][3], 0.f);
      }
    }

    if (rep < 7) {
      #pragma unroll
      for (int jj = 0; jj < 4; ++jj) {
        union { unsigned short u[8]; uint4 q; } pk;
        #pragma unroll
        for (int e = 0; e < 8; ++e) pk.u[e] = f2b(nxv[jj * 8 + e]);
        *(uint4*)&featT[cur ^ 1][pl * 264 + cph * 32 + jj * 8] = pk.q;
      }
    }
  }
}

extern "C" void kernel_launch(void* const* d_in, const int* in_sizes, int n_in,
                              void* d_out, int out_size, void* d_ws, size_t ws_size,
                              hipStream_t stream) {
  (void)in_sizes; (void)n_in; (void)out_size; (void)ws_size;
  const float* feat = (const float*)d_in[0];
  const float* cent = (const float*)d_in[1];
  const float* fcw  = (const float*)d_in[2];
  const float* fcb  = (const float*)d_in[3];
  float* out = (float*)d_out;
  char* ws = (char*)d_ws;
  float* cnT             = (float*)(ws);
  float* wt              = (float*)(ws + 81920);
  unsigned short* wks    = (unsigned short*)(ws + 344064);
  unsigned short* centf  = (unsigned short*)(ws + 475136);
  u8*    idxb            = (u8*)(ws + 1130496);
  float* fsq             = (float*)(ws + 1392640);
  int*   cntg            = (int*)(ws + 2441216);
  float* csq             = (float*)(ws + 2446336);
  float* chat            = (float*)(ws + 2451456);
  float* part            = (float*)(ws + 3762176);

  k0_cnorm<<<80, 256, 0, stream>>>(cent, cnT, cntg);
  k0_wprep<<<256, 256, 0, stream>>>(fcw, wks, wt);
  k1f_v8<<<512, 256, 0, stream>>>(feat, cnT, idxb, fsq, cntg, part, 0);   // chunks 0-31
  k1f_v4<<<512, 256, 0, stream>>>(feat, cnT, idxb, fsq, cntg, part, 32);  // chunks 32-63
  k2_cent<<<1280, 256, 0, stream>>>(part, cntg, wt, centf, csq, chat);
  k3b_gemm<<<512, 512, 0, stream>>>(feat, idxb, fsq, csq, centf, chat, wks, fcb, out);
}

// Round 22
// 388.026 us; speedup vs baseline: 1.8774x; 1.8774x over previous
//
#include <hip/hip_runtime.h>

// Refine: out = relu((1-a)*(W f) + a*chat[idx] + bias)
// a = exp(-(csq - 2*<f,cent[idx]> + fsq)/256), chat = W*cent
// idx = argmax_n <f, cnorm_n>
//
// FINAL (R16/R20-verified best: ~390 us, 2.4x over first passing version).
// ws layout (1 GiB available; ~88 MB used):
//  cnT    [256][80] f32        @ 0
//  wt     [256][256] f32       @ 81920
//  wks    [8][256][32] bf16    @ 344064
//  centf  [16][80][256] bf16   @ 475136
//  idxb   [16*16384] u8        @ 1130496
//  fsq    [16*16384] f32       @ 1392640
//  cnt    [16*80] i32          @ 2441216  (zeroed by k0_cnorm)
//  csq    [16*80] f32          @ 2446336
//  chat   [16][80][256] f32    @ 2451456
//  part   [16][64][80][256] f32 @ 3762176  (per-block sumx partials, NON-atomic)

typedef __bf16 bf16x8 __attribute__((ext_vector_type(8)));
typedef float  f32x4  __attribute__((ext_vector_type(4)));
typedef unsigned char u8;

__device__ __forceinline__ unsigned short f2b(float f) {
  unsigned u = __float_as_uint(f);
  return (unsigned short)((u + 0x7fffu + ((u >> 16) & 1u)) >> 16);
}
__device__ __forceinline__ float b2f(unsigned short s) {
  return __uint_as_float((unsigned)s << 16);
}

// ---------------- K0a: normalized centroids [c][n] + zero cntg ----------------
__global__ __launch_bounds__(256) void k0_cnorm(const float* __restrict__ cent,
                                                float* __restrict__ cnT,
                                                int* __restrict__ cntg) {
  int n = blockIdx.x, t = threadIdx.x;
  if (t < 16) cntg[n * 16 + t] = 0;
  float v = cent[n * 256 + t];
  float s = v * v;
  #pragma unroll
  for (int o = 32; o > 0; o >>= 1) s += __shfl_down(s, o, 64);
  __shared__ float red[4];
  if ((t & 63) == 0) red[t >> 6] = s;
  __syncthreads();
  float tot = red[0] + red[1] + red[2] + red[3];
  float dn = fmaxf(sqrtf(tot), 1e-12f);
  cnT[t * 80 + n] = v / dn;
}

// ---------------- K0b: W prep: bf16 k-sliced [k][o][32] + W^T f32 -------------
__global__ __launch_bounds__(256) void k0_wprep(const float* __restrict__ fcw,
                                                unsigned short* __restrict__ wks,
                                                float* __restrict__ wt) {
  int o = blockIdx.x, c = threadIdx.x;
  float w = fcw[o * 256 + c];
  wt[c * 256 + o] = w;
  wks[((c >> 5) * 256 + o) * 32 + (c & 31)] = f2b(w);
}

// ---- K1F: argmax (f32, exact, 2 class-halves) + fsq + counts + sumx ----------
// g[40] scalar, unroll 4, bounds(256,4): ~104 unified regs, 4 waves/SIMD,
// no spill. sumx: one-hot MFMA, 2 channel-half passes (acc[5][2] = 40 AGPR),
// feat re-reads L2/L3-hot, block-owned non-atomic partials.
__global__ __launch_bounds__(256, 4) void k1f(const float* __restrict__ feat,
                                              const float* __restrict__ cnT,
                                              u8* __restrict__ idxb,
                                              float* __restrict__ fsqg,
                                              int* __restrict__ cntg,
                                              float* __restrict__ part) {
  __shared__ alignas(8) u8 idxl[256];
  __shared__ int lh[80];
  const int b = blockIdx.x >> 6, chunk = blockIdx.x & 63;
  const int px0 = chunk << 8;
  const int t = threadIdx.x, wv = t >> 6, ln = t & 63, lo = ln & 15, hi = ln >> 4;
  if (t < 80) lh[t] = 0;
  __syncthreads();

  // ---- argmax: classes 0..39 (+fsq), then 40..79; exact merge ----
  const int pi = px0 | t;
  const float* fb = feat + (size_t)b * 256 * 16384 + pi;
  float best, fsq; int bi;
  {
    float g[40];
    #pragma unroll
    for (int n = 0; n < 40; ++n) g[n] = 0.f;
    fsq = 0.f;
    #pragma unroll 4
    for (int c = 0; c < 256; ++c) {
      float v = fb[(size_t)c * 16384];
      fsq = fmaf(v, v, fsq);
      const float* cr = cnT + c * 80;
      #pragma unroll
      for (int n = 0; n < 40; ++n) g[n] = fmaf(v, cr[n], g[n]);
    }
    best = g[0]; bi = 0;
    #pragma unroll
    for (int n = 1; n < 40; ++n) if (g[n] > best) { best = g[n]; bi = n; }
  }
  {
    float g[40];
    #pragma unroll
    for (int n = 0; n < 40; ++n) g[n] = 0.f;
    #pragma unroll 4
    for (int c = 0; c < 256; ++c) {
      float v = fb[(size_t)c * 16384];            // L2/L3-hot re-read
      const float* cr = cnT + c * 80 + 40;
      #pragma unroll
      for (int n = 0; n < 40; ++n) g[n] = fmaf(v, cr[n], g[n]);
    }
    float b2 = g[0]; int i2 = 40;
    #pragma unroll
    for (int n = 1; n < 40; ++n) if (g[n] > b2) { b2 = g[n]; i2 = 40 + n; }
    if (b2 > best) { best = b2; bi = i2; }        // ties keep lower index
  }
  idxb[b * 16384 + pi] = (u8)bi;
  fsqg[b * 16384 + pi] = fsq;
  idxl[t] = (u8)bi;
  atomicAdd(&lh[bi], 1);
  __syncthreads();
  if (t < 80) atomicAdd(&cntg[b * 80 + t], lh[t]);

  // ---- sumx: one-hot MFMA, 2 channel-half passes (acc[5][2] = 40 AGPR) ----
  const int chb = wv * 64;
  float* pb = part + ((size_t)(b * 64 + chunk) * 80) * 256;
  #pragma unroll 1
  for (int half = 0; half < 2; ++half) {
    f32x4 acc[5][2];
    f32x4 zz = {0.f, 0.f, 0.f, 0.f};
    #pragma unroll
    for (int mt = 0; mt < 5; ++mt) { acc[mt][0] = zz; acc[mt][1] = zz; }
    #pragma unroll 2
    for (int ks = 0; ks < 8; ++ks) {
      uint2 iv = *(const uint2*)&idxl[ks * 32 + hi * 8];
      int id[8];
      #pragma unroll
      for (int j = 0; j < 4; ++j) { id[j] = (iv.x >> (8 * j)) & 255; id[4 + j] = (iv.y >> (8 * j)) & 255; }
      bf16x8 bfr[2];
      #pragma unroll
      for (int n2 = 0; n2 < 2; ++n2) {
        int nt = half * 2 + n2;
        const float* bp = feat + ((size_t)b * 256 + chb + nt * 16 + lo) * 16384 + px0 + ks * 32 + hi * 8;
        float4 v0 = *(const float4*)bp;
        float4 v1 = *(const float4*)(bp + 4);
        union { unsigned short u[8]; bf16x8 v; } bb;
        bb.u[0] = f2b(v0.x); bb.u[1] = f2b(v0.y); bb.u[2] = f2b(v0.z); bb.u[3] = f2b(v0.w);
        bb.u[4] = f2b(v1.x); bb.u[5] = f2b(v1.y); bb.u[6] = f2b(v1.z); bb.u[7] = f2b(v1.w);
        bfr[n2] = bb.v;
      }
      #pragma unroll
      for (int mt = 0; mt < 5; ++mt) {
        int row = mt * 16 + lo;
        union { unsigned short u[8]; bf16x8 v; } ma;
        #pragma unroll
        for (int j = 0; j < 8; ++j) ma.u[j] = (id[j] == row) ? (unsigned short)0x3F80 : (unsigned short)0;
        #pragma unroll
        for (int n2 = 0; n2 < 2; ++n2)
          acc[mt][n2] = __builtin_amdgcn_mfma_f32_16x16x32_bf16(ma.v, bfr[n2], acc[mt][n2], 0, 0, 0);
      }
    }
    // block-owned partial write: NO atomics, coalesced
    #pragma unroll
    for (int mt = 0; mt < 5; ++mt)
      #pragma unroll
      for (int n2 = 0; n2 < 2; ++n2)
        #pragma unroll
        for (int r = 0; r < 4; ++r)
          pb[(mt * 16 + hi * 4 + r) * 256 + chb + (half * 2 + n2) * 16 + lo] = acc[mt][n2][r];
  }
}

// -------- K2: cent = Σ64 partials / max(cnt,1); csq; centf; chat = W*cent -----
__global__ __launch_bounds__(256) void k2_cent(const float* __restrict__ part,
                                               const int* __restrict__ cntg,
                                               const float* __restrict__ wt,
                                               unsigned short* __restrict__ centf,
                                               float* __restrict__ csqg,
                                               float* __restrict__ chatg) {
  int bn = blockIdx.x; int b = bn / 80, n = bn - b * 80; int t = threadIdx.x;
  float dn = fmaxf((float)cntg[bn], 1.0f);
  float s = 0.f;
  const float* pp = part + ((size_t)(b * 64) * 80 + n) * 256 + t;
  #pragma unroll 8
  for (int ck = 0; ck < 64; ++ck) s += pp[(size_t)ck * 80 * 256];
  float cv = s / dn;
  __shared__ float cl[256];
  __shared__ float red[4];
  cl[t] = cv;
  centf[(size_t)bn * 256 + t] = f2b(cv);
  float q = cv * cv;
  #pragma unroll
  for (int o = 32; o > 0; o >>= 1) q += __shfl_down(q, o, 64);
  if ((t & 63) == 0) red[t >> 6] = q;
  __syncthreads();
  if (t == 0) csqg[bn] = red[0] + red[1] + red[2] + red[3];
  float acc = 0.f;
  #pragma unroll 4
  for (int c = 0; c < 256; ++c) acc = fmaf(wt[c * 256 + t], cl[c], acc);
  chatg[(size_t)bn * 256 + t] = acc;
}

// ---------------- K3b: pipelined W-in-registers MFMA GEMM + alpha + epilogue --
__global__ __launch_bounds__(512) void k3b_gemm(const float* __restrict__ feat,
    const u8* __restrict__ idxb, const float* __restrict__ fsqg,
    const float* __restrict__ csqg, const unsigned short* __restrict__ centf,
    const float* __restrict__ chatg, const unsigned short* __restrict__ wks,
    const float* __restrict__ fcb, float* __restrict__ out) {
  __shared__ alignas(16) unsigned short featT[2][64 * 264];  // double-buffered
  __shared__ float alphal[64];
  __shared__ int cidl[64];
  const int t = threadIdx.x;
  const int w = t >> 6, ln = t & 63, lo = ln & 15, hi = ln >> 4;
  const int pl = ln, cph = w;

  bf16x8 wf[2][8];
  #pragma unroll
  for (int ml = 0; ml < 2; ++ml)
    #pragma unroll
    for (int ks = 0; ks < 8; ++ks)
      wf[ml][ks] = *(const bf16x8*)&wks[((size_t)ks * 256 + (w * 2 + ml) * 16 + lo) * 32 + hi * 8];
  f32x4 bias2[2];
  #pragma unroll
  for (int ml = 0; ml < 2; ++ml)
    bias2[ml] = *(const f32x4*)&fcb[w * 32 + ml * 16 + hi * 4];

  const int tile0 = blockIdx.x * 8;
  {
    int b = tile0 >> 8, p0 = (tile0 & 255) << 6;
    const float* fb = feat + ((size_t)b * 256 + cph * 32) * 16384 + p0 + pl;
    #pragma unroll
    for (int jj = 0; jj < 4; ++jj) {
      union { unsigned short u[8]; uint4 q; } pk;
      #pragma unroll
      for (int e = 0; e < 8; ++e) pk.u[e] = f2b(fb[(size_t)(jj * 8 + e) * 16384]);
      *(uint4*)&featT[0][pl * 264 + cph * 32 + jj * 8] = pk.q;
    }
  }

  float nxv[32];
  for (int rep = 0; rep < 8; ++rep) {
    const int cur = rep & 1;
    const int tile = tile0 + rep;
    const int b = tile >> 8, p0 = (tile & 255) << 6;

    __syncthreads();

    if (rep < 7) {
      int t2 = tile + 1;
      int b2 = t2 >> 8, p02 = (t2 & 255) << 6;
      const float* fb2 = feat + ((size_t)b2 * 256 + cph * 32) * 16384 + p02 + pl;
      #pragma unroll
      for (int e = 0; e < 32; ++e) nxv[e] = fb2[(size_t)e * 16384];
    }

    {
      int p = t >> 3, sub = t & 7;
      int cid = idxb[b * 16384 + p0 + p];
      const unsigned short* cw = centf + ((size_t)b * 80 + cid) * 256 + sub * 32;
      const unsigned short* fr = &featT[cur][p * 264 + sub * 32];
      float sel = 0.f;
      #pragma unroll
      for (int j = 0; j < 4; ++j) {
        uint4 cc = *(const uint4*)&cw[j * 8];
        uint4 ff = *(const uint4*)&fr[j * 8];
        sel = fmaf(b2f((unsigned short)(ff.x & 0xffff)), b2f((unsigned short)(cc.x & 0xffff)), sel);
        sel = fmaf(b2f((unsigned short)(ff.x >> 16)),    b2f((unsigned short)(cc.x >> 16)),    sel);
        sel = fmaf(b2f((unsigned short)(ff.y & 0xffff)), b2f((unsigned short)(cc.y & 0xffff)), sel);
        sel = fmaf(b2f((unsigned short)(ff.y >> 16)),    b2f((unsigned short)(cc.y >> 16)),    sel);
        sel = fmaf(b2f((unsigned short)(ff.z & 0xffff)), b2f((unsigned short)(cc.z & 0xffff)), sel);
        sel = fmaf(b2f((unsigned short)(ff.z >> 16)),    b2f((unsigned short)(cc.z >> 16)),    sel);
        sel = fmaf(b2f((unsigned short)(ff.w & 0xffff)), b2f((unsigned short)(cc.w & 0xffff)), sel);
        sel = fmaf(b2f((unsigned short)(ff.w >> 16)),    b2f((unsigned short)(cc.w >> 16)),    sel);
      }
      sel += __shfl_xor(sel, 1, 64);
      sel += __shfl_xor(sel, 2, 64);
      sel += __shfl_xor(sel, 4, 64);
      if (sub == 0) {
        float fsq = fsqg[b * 16384 + p0 + p];
        float msq = (csqg[b * 80 + cid] - 2.f * sel + fsq) * (1.f / 256.f);
        alphal[p] = expf(-msq);
        cidl[p] = cid;
      }
    }

    f32x4 acc[2][4];
    f32x4 zz = {0.f, 0.f, 0.f, 0.f};
    #pragma unroll
    for (int ml = 0; ml < 2; ++ml)
      #pragma unroll
      for (int pt = 0; pt < 4; ++pt) acc[ml][pt] = zz;

    #pragma unroll
    for (int ks = 0; ks < 8; ++ks) {
      bf16x8 bfr[4];
      #pragma unroll
      for (int pt = 0; pt < 4; ++pt)
        bfr[pt] = *(const bf16x8*)&featT[cur][(pt * 16 + lo) * 264 + ks * 32 + hi * 8];
      #pragma unroll
      for (int ml = 0; ml < 2; ++ml)
        #pragma unroll
        for (int pt = 0; pt < 4; ++pt)
          acc[ml][pt] = __builtin_amdgcn_mfma_f32_16x16x32_bf16(wf[ml][ks], bfr[pt], acc[ml][pt], 0, 0, 0);
    }
    __syncthreads();

    #pragma unroll
    for (int pt = 0; pt < 4; ++pt) {
      int plx = pt * 16 + lo;
      int p = p0 + plx;
      float a = alphal[plx];
      float om = 1.f - a;
      const float* crow = chatg + ((size_t)b * 80 + cidl[plx]) * 256;
      #pragma unroll
      for (int ml = 0; ml < 2; ++ml) {
        int o0 = w * 32 + ml * 16 + hi * 4;
        float4 c4 = *(const float4*)&crow[o0];
        size_t ob = ((size_t)b * 256 + o0) * 16384 + p;
        out[ob            ] = fmaxf(fmaf(a, c4.x, om * acc[ml][pt][0]) + bias2[ml][0], 0.f);
        out[ob + 16384    ] = fmaxf(fmaf(a, c4.y, om * acc[ml][pt][1]) + bias2[ml][1], 0.f);
        out[ob + 2 * 16384] = fmaxf(fmaf(a, c4.z, om * acc[ml][pt][2]) + bias2[ml][2], 0.f);
        out[ob + 3 * 16384] = fmaxf(fmaf(a, c4.w, om * acc[ml][pt][3]) + bias2[ml][3], 0.f);
      }
    }

    if (rep < 7) {
      #pragma unroll
      for (int jj = 0; jj < 4; ++jj) {
        union { unsigned short u[8]; uint4 q; } pk;
        #pragma unroll
        for (int e = 0; e < 8; ++e) pk.u[e] = f2b(nxv[jj * 8 + e]);
        *(uint4*)&featT[cur ^ 1][pl * 264 + cph * 32 + jj * 8] = pk.q;
      }
    }
  }
}

extern "C" void kernel_launch(void* const* d_in, const int* in_sizes, int n_in,
                              void* d_out, int out_size, void* d_ws, size_t ws_size,
                              hipStream_t stream) {
  (void)in_sizes; (void)n_in; (void)out_size; (void)ws_size;
  const float* feat = (const float*)d_in[0];
  const float* cent = (const float*)d_in[1];
  const float* fcw  = (const float*)d_in[2];
  const float* fcb  = (const float*)d_in[3];
  float* out = (float*)d_out;
  char* ws = (char*)d_ws;
  float* cnT             = (float*)(ws);
  float* wt              = (float*)(ws + 81920);
  unsigned short* wks    = (unsigned short*)(ws + 344064);
  unsigned short* centf  = (unsigned short*)(ws + 475136);
  u8*    idxb            = (u8*)(ws + 1130496);
  float* fsq             = (float*)(ws + 1392640);
  int*   cntg            = (int*)(ws + 2441216);
  float* csq             = (float*)(ws + 2446336);
  float* chat            = (float*)(ws + 2451456);
  float* part            = (float*)(ws + 3762176);

  k0_cnorm<<<80, 256, 0, stream>>>(cent, cnT, cntg);
  k0_wprep<<<256, 256, 0, stream>>>(fcw, wks, wt);
  k1f<<<1024, 256, 0, stream>>>(feat, cnT, idxb, fsq, cntg, part);
  k2_cent<<<1280, 256, 0, stream>>>(part, cntg, wt, centf, csq, chat);
  k3b_gemm<<<512, 512, 0, stream>>>(feat, idxb, fsq, csq, centf, chat, wks, fcb, out);
}